// Round 2
// baseline (82.686 us; speedup 1.0000x reference)
//
#include <hip/hip_runtime.h>
#include <hip/hip_bf16.h>

// Poincare pairwise distance, c=1:
//   d(x,p) = acosh(1 + 2*||x-p||^2 / ((1-||x||^2)(1-||p||^2)))
// B=16384, N=4096, D=64. Output 16384x4096 f32 (256 MiB) -> write-bound.
// GEMM via bf16 MFMA computed TRANSPOSED (P rows x X cols) so each lane
// holds 4 consecutive output columns -> dwordx4 stores.

constexpr int BATCH = 16384;
constexpr int NCON  = 4096;
constexpr int DIM   = 64;
constexpr int TM    = 128;          // emb rows per block
constexpr int TN    = 128;          // proto rows per block
constexpr int NT_N  = NCON / TN;    // 32 tiles along N
constexpr float LN2 = 0.6931471805599453f;

typedef float  f32x4  __attribute__((ext_vector_type(4)));
typedef __bf16 bf16x8 __attribute__((ext_vector_type(8)));

__global__ __launch_bounds__(256, 4)
void poincare_pairwise_kernel(const float* __restrict__ emb,
                              const float* __restrict__ proto,
                              float* __restrict__ out)
{
    // bf16 tiles, XOR-swizzled along k (k ^= (row&7)<<3) to kill the
    // stride-128B bank conflict on ds_read_b128.
    __shared__ __bf16 As[TM * DIM];   // 16 KiB (emb)
    __shared__ __bf16 Bs[TN * DIM];   // 16 KiB (proto)
    __shared__ float  x2s[TM];
    __shared__ float  p2s[TN];

    const int tid = threadIdx.x;
    const int bid = blockIdx.x;
    const int mt  = bid >> 5;          // 128 tiles along M
    const int nt  = bid & (NT_N - 1);  // 32 tiles along N
    const int m0  = mt * TM;
    const int n0  = nt * TN;

    // ---------- stage A tile (emb: 128 x 64) ----------
    #pragma unroll
    for (int p = 0; p < 8; ++p) {
        int flat = p * 256 + tid;
        int row  = flat >> 4;
        int kq   = flat & 15;
        f32x4 v = *reinterpret_cast<const f32x4*>(emb + (size_t)(m0 + row) * DIM + kq * 4);
        float ss = v.x * v.x + v.y * v.y + v.z * v.z + v.w * v.w;
        ss += __shfl_xor(ss, 1);
        ss += __shfl_xor(ss, 2);
        ss += __shfl_xor(ss, 4);
        ss += __shfl_xor(ss, 8);
        if (kq == 0) x2s[row] = ss;
        __bf16 b4[4] = {(__bf16)v.x, (__bf16)v.y, (__bf16)v.z, (__bf16)v.w};
        int ke = (kq * 4) ^ ((row & 7) << 3);
        *reinterpret_cast<uint2*>(&As[row * DIM + ke]) = *reinterpret_cast<const uint2*>(b4);
    }
    // ---------- stage B tile (proto: 128 x 64) ----------
    #pragma unroll
    for (int p = 0; p < 8; ++p) {
        int flat = p * 256 + tid;
        int row  = flat >> 4;
        int kq   = flat & 15;
        f32x4 v = *reinterpret_cast<const f32x4*>(proto + (size_t)(n0 + row) * DIM + kq * 4);
        float ss = v.x * v.x + v.y * v.y + v.z * v.z + v.w * v.w;
        ss += __shfl_xor(ss, 1);
        ss += __shfl_xor(ss, 2);
        ss += __shfl_xor(ss, 4);
        ss += __shfl_xor(ss, 8);
        if (kq == 0) p2s[row] = ss;
        __bf16 b4[4] = {(__bf16)v.x, (__bf16)v.y, (__bf16)v.z, (__bf16)v.w};
        int ke = (kq * 4) ^ ((row & 7) << 3);
        *reinterpret_cast<uint2*>(&Bs[row * DIM + ke]) = *reinterpret_cast<const uint2*>(b4);
    }
    __syncthreads();

    // ---------- MFMA: wave owns 64(proto) x 64(emb), TRANSPOSED ----------
    const int lane = tid & 63;
    const int wid  = tid >> 6;
    const int wp   = wid >> 1;         // 2 waves along proto dim
    const int wx   = wid & 1;          // 2 waves along emb dim
    const int lr   = lane & 15;
    const int lk   = (lane >> 4) * 8;

    f32x4 acc[4][4] = {};              // [proto frag][emb frag]
    #pragma unroll
    for (int kk = 0; kk < 2; ++kk) {
        bf16x8 pfrag[4], xfrag[4];
        #pragma unroll
        for (int i = 0; i < 4; ++i) {
            int prow = wp * 64 + i * 16 + lr;
            int kep  = (kk * 32 + lk) ^ ((prow & 7) << 3);
            pfrag[i] = *reinterpret_cast<const bf16x8*>(&Bs[prow * DIM + kep]);
            int xrow = wx * 64 + i * 16 + lr;
            int kex  = (kk * 32 + lk) ^ ((xrow & 7) << 3);
            xfrag[i] = *reinterpret_cast<const bf16x8*>(&As[xrow * DIM + kex]);
        }
        #pragma unroll
        for (int i = 0; i < 4; ++i)
            #pragma unroll
            for (int n = 0; n < 4; ++n)
                acc[i][n] = __builtin_amdgcn_mfma_f32_16x16x32_bf16(
                    pfrag[i], xfrag[n], acc[i][n], 0, 0, 0);
    }

    // ---------- epilogue ----------
    // D layout: col = lane&15 -> emb row; row = (lane>>4)*4+j -> proto idx.
    // => lane holds 4 CONSECUTIVE proto columns -> dwordx4 store.
    const int g4 = (lane >> 4) * 4;
    #pragma unroll
    for (int xf = 0; xf < 4; ++xf) {
        int   xloc = wx * 64 + xf * 16 + lr;
        float x2   = x2s[xloc];
        float omx  = 1.0f - x2;
        float* rowp = out + (size_t)(m0 + xloc) * NCON + n0;
        #pragma unroll
        for (int pf = 0; pf < 4; ++pf) {
            int   ploc = wp * 64 + pf * 16 + g4;
            f32x4 p2   = *reinterpret_cast<const f32x4*>(&p2s[ploc]);
            f32x4 dv;
            #pragma unroll
            for (int j = 0; j < 4; ++j) {
                float xp  = acc[pf][xf][j];
                float sq  = fmaxf(x2 + p2[j] - 2.0f * xp, 0.0f);
                float den = omx * (1.0f - p2[j]);      // >= ~0.45, no EPS clamp needed
                float t   = 2.0f * sq * __builtin_amdgcn_rcpf(den);
                float s   = __builtin_amdgcn_sqrtf(t * (t + 2.0f));
                dv[j]     = LN2 * __builtin_amdgcn_logf(1.0f + t + s);
            }
            __builtin_nontemporal_store(dv, reinterpret_cast<f32x4*>(rowp + ploc));
        }
    }
}

extern "C" void kernel_launch(void* const* d_in, const int* in_sizes, int n_in,
                              void* d_out, int out_size, void* d_ws, size_t ws_size,
                              hipStream_t stream) {
    const float* emb   = (const float*)d_in[0];
    const float* proto = (const float*)d_in[1];
    float* out = (float*)d_out;

    dim3 grid((BATCH / TM) * (NCON / TN));  // 4096
    dim3 block(256);
    poincare_pairwise_kernel<<<grid, block, 0, stream>>>(emb, proto, out);
}

// Round 3
// 74.144 us; speedup vs baseline: 1.1152x; 1.1152x over previous
//
#include <hip/hip_runtime.h>
#include <hip/hip_bf16.h>

// Poincare pairwise distance, c=1:
//   d(x,p) = acosh(1 + 2*||x-p||^2 / ((1-||x||^2)(1-||p||^2)))
// B=16384, N=4096, D=64. Output 16384x4096 f32 (256 MiB) -> write-bound.
// bf16 MFMA (transposed: proto as A, emb as B) + LDS epilogue transpose so
// global stores are lane-consecutive dwordx4 (full-line coalescing).

constexpr int BATCH = 16384;
constexpr int NCON  = 4096;
constexpr int DIM   = 64;
constexpr int TM    = 128;          // emb rows per block
constexpr int TN    = 128;          // proto rows per block
constexpr int NT_N  = NCON / TN;    // 32 tiles along N
constexpr float LN2 = 0.6931471805599453f;

typedef float  f32x4  __attribute__((ext_vector_type(4)));
typedef __bf16 bf16x8 __attribute__((ext_vector_type(8)));

__global__ __launch_bounds__(256, 4)
void poincare_pairwise_kernel(const float* __restrict__ emb,
                              const float* __restrict__ proto,
                              float* __restrict__ out)
{
    // As/Bs: bf16 input tiles, XOR-swizzled along k (k ^= (row&7)<<3).
    // Es: 32x128 f32 epilogue transpose buffer — ALIASES As/Bs (dead after
    // fragment loads; barrier separates the lifetimes).
    __shared__ __align__(16) char smem[TM * DIM * 2 + TN * DIM * 2]; // 32 KiB
    __bf16* As = reinterpret_cast<__bf16*>(smem);
    __bf16* Bs = reinterpret_cast<__bf16*>(smem + TM * DIM * 2);
    float*  Es = reinterpret_cast<float*>(smem);                    // 16 KiB used
    __shared__ float x2s[TM];
    __shared__ float p2s[TN];

    const int tid = threadIdx.x;
    const int bid = blockIdx.x;
    const int mt  = bid >> 5;          // 128 tiles along M
    const int nt  = bid & (NT_N - 1);  // 32 tiles along N
    const int m0  = mt * TM;
    const int n0  = nt * TN;

    // ---------- stage A tile (emb: 128 x 64) ----------
    #pragma unroll
    for (int p = 0; p < 8; ++p) {
        int flat = p * 256 + tid;
        int row  = flat >> 4;
        int kq   = flat & 15;
        f32x4 v = *reinterpret_cast<const f32x4*>(emb + (size_t)(m0 + row) * DIM + kq * 4);
        float ss = v.x * v.x + v.y * v.y + v.z * v.z + v.w * v.w;
        ss += __shfl_xor(ss, 1);
        ss += __shfl_xor(ss, 2);
        ss += __shfl_xor(ss, 4);
        ss += __shfl_xor(ss, 8);
        if (kq == 0) x2s[row] = ss;
        __bf16 b4[4] = {(__bf16)v.x, (__bf16)v.y, (__bf16)v.z, (__bf16)v.w};
        int ke = (kq * 4) ^ ((row & 7) << 3);
        *reinterpret_cast<uint2*>(&As[row * DIM + ke]) = *reinterpret_cast<const uint2*>(b4);
    }
    // ---------- stage B tile (proto: 128 x 64) ----------
    #pragma unroll
    for (int p = 0; p < 8; ++p) {
        int flat = p * 256 + tid;
        int row  = flat >> 4;
        int kq   = flat & 15;
        f32x4 v = *reinterpret_cast<const f32x4*>(proto + (size_t)(n0 + row) * DIM + kq * 4);
        float ss = v.x * v.x + v.y * v.y + v.z * v.z + v.w * v.w;
        ss += __shfl_xor(ss, 1);
        ss += __shfl_xor(ss, 2);
        ss += __shfl_xor(ss, 4);
        ss += __shfl_xor(ss, 8);
        if (kq == 0) p2s[row] = ss;
        __bf16 b4[4] = {(__bf16)v.x, (__bf16)v.y, (__bf16)v.z, (__bf16)v.w};
        int ke = (kq * 4) ^ ((row & 7) << 3);
        *reinterpret_cast<uint2*>(&Bs[row * DIM + ke]) = *reinterpret_cast<const uint2*>(b4);
    }
    __syncthreads();

    // ---------- fragment loads ----------
    const int lane = tid & 63;
    const int wid  = tid >> 6;
    const int wp   = wid >> 1;         // 2 waves along proto dim
    const int wx   = wid & 1;          // 2 waves along emb dim
    const int lr   = lane & 15;
    const int g    = lane >> 4;        // quarter-wave index 0..3
    const int lk   = g * 8;

    bf16x8 pfrag[2][4], xfrag[2][4];
    #pragma unroll
    for (int kk = 0; kk < 2; ++kk) {
        #pragma unroll
        for (int i = 0; i < 4; ++i) {
            int prow = wp * 64 + i * 16 + lr;
            int kep  = (kk * 32 + lk) ^ ((prow & 7) << 3);
            pfrag[kk][i] = *reinterpret_cast<const bf16x8*>(&Bs[prow * DIM + kep]);
            int xrow = wx * 64 + i * 16 + lr;
            int kex  = (kk * 32 + lk) ^ ((xrow & 7) << 3);
            xfrag[kk][i] = *reinterpret_cast<const bf16x8*>(&As[xrow * DIM + kex]);
        }
    }
    __syncthreads();   // As/Bs lifetime ends; Es (aliased) may be written after this

    // ---------- MFMA: wave owns 64(proto) x 64(emb) ----------
    f32x4 acc[4][4] = {};              // [proto frag][emb frag]
    #pragma unroll
    for (int kk = 0; kk < 2; ++kk)
        #pragma unroll
        for (int i = 0; i < 4; ++i)
            #pragma unroll
            for (int n = 0; n < 4; ++n)
                acc[i][n] = __builtin_amdgcn_mfma_f32_16x16x32_bf16(
                    pfrag[kk][i], xfrag[kk][n], acc[i][n], 0, 0, 0);

    // ---------- epilogue: distance + LDS transpose + coalesced store ----------
    // D layout: col = lane&15 -> emb row; row = (lane>>4)*4+j -> proto idx.
    // Chunk xf: 32 emb rows ({xf*16..+15} U {64+xf*16..+15}) x 128 proto cols.
    // LDS slot-swizzle: slot ^= (row&7)  (4-float slots, conflict-free both sides).
    #pragma unroll
    for (int xf = 0; xf < 4; ++xf) {
        int   xloc = wx * 64 + xf * 16 + lr;
        float x2   = x2s[xloc];
        float omx  = 1.0f - x2;
        int   lrow = wx * 16 + lr;       // chunk-local row 0..31
        #pragma unroll
        for (int pf = 0; pf < 4; ++pf) {
            int   slot = wp * 16 + pf * 4 + g;   // 4-float slot 0..31
            f32x4 p2   = *reinterpret_cast<const f32x4*>(&p2s[slot * 4]);
            f32x4 dv;
            #pragma unroll
            for (int j = 0; j < 4; ++j) {
                float xp  = acc[pf][xf][j];
                float sq  = fmaxf(x2 + p2[j] - 2.0f * xp, 0.0f);
                float den = omx * (1.0f - p2[j]);     // >= ~0.45, no EPS clamp needed
                float t   = 2.0f * sq * __builtin_amdgcn_rcpf(den);
                float s   = __builtin_amdgcn_sqrtf(t * (t + 2.0f));
                dv[j]     = LN2 * __builtin_amdgcn_logf(1.0f + t + s);
            }
            int sw = slot ^ (lrow & 7);
            *reinterpret_cast<f32x4*>(&Es[lrow * 128 + sw * 4]) = dv;
        }
        __syncthreads();
        #pragma unroll
        for (int i = 0; i < 4; ++i) {
            int fi = i * 256 + tid;          // 0..1023 float4s
            int r  = fi >> 5;                // chunk-local row 0..31
            int s  = fi & 31;                // linear slot
            f32x4 v = *reinterpret_cast<const f32x4*>(&Es[r * 128 + (s ^ (r & 7)) * 4]);
            int erow = (r >> 4) * 64 + xf * 16 + (r & 15);
            *reinterpret_cast<f32x4*>(out + (size_t)(m0 + erow) * NCON + n0 + s * 4) = v;
        }
        __syncthreads();
    }
}

extern "C" void kernel_launch(void* const* d_in, const int* in_sizes, int n_in,
                              void* d_out, int out_size, void* d_ws, size_t ws_size,
                              hipStream_t stream) {
    const float* emb   = (const float*)d_in[0];
    const float* proto = (const float*)d_in[1];
    float* out = (float*)d_out;

    dim3 grid((BATCH / TM) * (NCON / TN));  // 4096
    dim3 block(256);
    poincare_pairwise_kernel<<<grid, block, 0, stream>>>(emb, proto, out);
}

// Round 4
// 72.822 us; speedup vs baseline: 1.1355x; 1.0182x over previous
//
#include <hip/hip_runtime.h>
#include <hip/hip_bf16.h>

// Poincare pairwise distance, c=1:
//   d(x,p) = acosh(1 + 2*||x-p||^2 / ((1-||x||^2)(1-||p||^2)))
// B=16384, N=4096, D=64. Output 16384x4096 f32 (256 MiB) -> write-bound.
//
// Structure (round 4): 64 emb x 128 proto tile, 256 threads, grid 8192.
// Each wave owns 16 emb rows x 128 protos: acc = 8 x f32x4 (32 VGPR),
// proto fragments streamed per k-step -> no spills at launch_bounds(256,4).
// ONE barrier total; epilogue has no barriers so waves' stores spread out.
// Epilogue: rcp(den) split into rcp(1-x2)*rcp(1-p2), rp precomputed per
// proto at staging -> 2 transcendentals + ~10 VALU per element.

constexpr int BATCH = 16384;
constexpr int NCON  = 4096;
constexpr int DIM   = 64;
constexpr int TM    = 64;           // emb rows per block
constexpr int TN    = 128;          // proto rows per block
constexpr int NT_N  = NCON / TN;    // 32 tiles along N
constexpr float LN2 = 0.6931471805599453f;

typedef float  f32x4  __attribute__((ext_vector_type(4)));
typedef __bf16 bf16x8 __attribute__((ext_vector_type(8)));

__global__ __launch_bounds__(256, 4)
void poincare_pairwise_kernel(const float* __restrict__ emb,
                              const float* __restrict__ proto,
                              float* __restrict__ out)
{
    // bf16 tiles, XOR-swizzled along k (k ^= (row&7)<<3) for conflict-free
    // ds_read_b128 fragment loads.
    __shared__ __bf16 As[TM * DIM];   // 8 KiB  (emb)
    __shared__ __bf16 Bs[TN * DIM];   // 16 KiB (proto)
    __shared__ float  x2s[TM];
    __shared__ float  p2s[TN];
    __shared__ float  rps[TN];        // rcp(1 - p2)

    const int tid = threadIdx.x;
    const int bid = blockIdx.x;
    const int mt  = bid >> 5;          // 256 tiles along M
    const int nt  = bid & (NT_N - 1);  // 32 tiles along N
    const int m0  = mt * TM;
    const int n0  = nt * TN;

    // ---------- stage A tile (emb: 64 x 64) ----------
    #pragma unroll
    for (int p = 0; p < 4; ++p) {
        int flat = p * 256 + tid;
        int row  = flat >> 4;
        int kq   = flat & 15;
        f32x4 v = *reinterpret_cast<const f32x4*>(emb + (size_t)(m0 + row) * DIM + kq * 4);
        float ss = v.x * v.x + v.y * v.y + v.z * v.z + v.w * v.w;
        ss += __shfl_xor(ss, 1);
        ss += __shfl_xor(ss, 2);
        ss += __shfl_xor(ss, 4);
        ss += __shfl_xor(ss, 8);
        if (kq == 0) x2s[row] = ss;
        __bf16 b4[4] = {(__bf16)v.x, (__bf16)v.y, (__bf16)v.z, (__bf16)v.w};
        int ke = (kq * 4) ^ ((row & 7) << 3);
        *reinterpret_cast<uint2*>(&As[row * DIM + ke]) = *reinterpret_cast<const uint2*>(b4);
    }
    // ---------- stage B tile (proto: 128 x 64) ----------
    #pragma unroll
    for (int p = 0; p < 8; ++p) {
        int flat = p * 256 + tid;
        int row  = flat >> 4;
        int kq   = flat & 15;
        f32x4 v = *reinterpret_cast<const f32x4*>(proto + (size_t)(n0 + row) * DIM + kq * 4);
        float ss = v.x * v.x + v.y * v.y + v.z * v.z + v.w * v.w;
        ss += __shfl_xor(ss, 1);
        ss += __shfl_xor(ss, 2);
        ss += __shfl_xor(ss, 4);
        ss += __shfl_xor(ss, 8);
        if (kq == 0) {
            p2s[row] = ss;
            rps[row] = __builtin_amdgcn_rcpf(1.0f - ss);
        }
        __bf16 b4[4] = {(__bf16)v.x, (__bf16)v.y, (__bf16)v.z, (__bf16)v.w};
        int ke = (kq * 4) ^ ((row & 7) << 3);
        *reinterpret_cast<uint2*>(&Bs[row * DIM + ke]) = *reinterpret_cast<const uint2*>(b4);
    }
    __syncthreads();   // the ONLY barrier

    // ---------- MFMA: wave owns 16 emb rows x 128 protos ----------
    const int lane = tid & 63;
    const int wid  = tid >> 6;         // wave -> emb 16-row strip
    const int lr   = lane & 15;
    const int g    = lane >> 4;
    const int lk   = g * 8;

    // emb fragment (B operand), both k-steps: 8 VGPRs
    bf16x8 xfrag[2];
    #pragma unroll
    for (int kk = 0; kk < 2; ++kk) {
        int xrow = wid * 16 + lr;
        int ke   = (kk * 32 + lk) ^ ((xrow & 7) << 3);
        xfrag[kk] = *reinterpret_cast<const bf16x8*>(&As[xrow * DIM + ke]);
    }

    f32x4 acc[8] = {};                 // [proto frag]; 32 VGPRs
    #pragma unroll
    for (int kk = 0; kk < 2; ++kk) {
        bf16x8 pfrag[8];
        #pragma unroll
        for (int pf = 0; pf < 8; ++pf) {
            int prow = pf * 16 + lr;
            int kep  = (kk * 32 + lk) ^ ((prow & 7) << 3);
            pfrag[pf] = *reinterpret_cast<const bf16x8*>(&Bs[prow * DIM + kep]);
        }
        #pragma unroll
        for (int pf = 0; pf < 8; ++pf)
            acc[pf] = __builtin_amdgcn_mfma_f32_16x16x32_bf16(
                pfrag[pf], xfrag[kk], acc[pf], 0, 0, 0);
    }

    // ---------- epilogue: distance + store (no barriers) ----------
    // D layout: col = lane&15 -> emb row (lr); row = g*4+j -> proto idx.
    // Lane stores 4 consecutive protos per fragment -> dwordx4.
    const float x2   = x2s[wid * 16 + lr];
    const float crow = 2.0f * __builtin_amdgcn_rcpf(1.0f - x2);
    float* rowp = out + (size_t)(m0 + wid * 16 + lr) * NCON + n0;
    #pragma unroll
    for (int pf = 0; pf < 8; ++pf) {
        int   col = pf * 16 + g * 4;
        f32x4 p2  = *reinterpret_cast<const f32x4*>(&p2s[col]);   // broadcast
        f32x4 rp  = *reinterpret_cast<const f32x4*>(&rps[col]);   // broadcast
        f32x4 dv;
        #pragma unroll
        for (int j = 0; j < 4; ++j) {
            float xp = acc[pf][j];
            float sq = fmaxf(x2 + p2[j] - 2.0f * xp, 0.0f);
            float t  = sq * crow * rp[j];
            float s  = __builtin_amdgcn_sqrtf(t * (t + 2.0f));
            dv[j]    = LN2 * __builtin_amdgcn_logf(1.0f + t + s);
        }
        *reinterpret_cast<f32x4*>(rowp + col) = dv;
    }
}

extern "C" void kernel_launch(void* const* d_in, const int* in_sizes, int n_in,
                              void* d_out, int out_size, void* d_ws, size_t ws_size,
                              hipStream_t stream) {
    const float* emb   = (const float*)d_in[0];
    const float* proto = (const float*)d_in[1];
    float* out = (float*)d_out;

    dim3 grid((BATCH / TM) * (NCON / TN));  // 256 * 32 = 8192
    dim3 block(256);
    poincare_pairwise_kernel<<<grid, block, 0, stream>>>(emb, proto, out);
}